// Round 11
// baseline (307.057 us; speedup 1.0000x reference)
//
#include <hip/hip_runtime.h>
#include <hip/hip_bf16.h>

// Problem constants
#define B_  8
#define S_  2048
#define H_  1024
#define P_  4096
#define K_  2048   // 2*H
#define M_  32768  // B*P
#define NT_ 32     // K-tiles (BK=64)

typedef unsigned short u16;
using bf16x8 = __attribute__((ext_vector_type(8))) short;   // 8 bf16 = 4 VGPRs
using f32x4  = __attribute__((ext_vector_type(4))) float;

#define AS1 __attribute__((address_space(1)))
#define AS3 __attribute__((address_space(3)))

__device__ inline u16 f2bf(float f) {
  union { float f; unsigned u; } c; c.f = f;
  unsigned u = c.u;
  unsigned r = (u + 0x7fffu + ((u >> 16) & 1u)) >> 16;  // RNE
  return (u16)r;
}

// ---- prep 1: hidden fp32 -> bf16 ---------------------------------------
__global__ void cvt_hidden_k(const float4* __restrict__ src,
                             ushort4* __restrict__ dst, int n4) {
  int i = blockIdx.x * blockDim.x + threadIdx.x;
  int stride = gridDim.x * blockDim.x;
  for (; i < n4; i += stride) {
    float4 v = src[i];
    ushort4 o;
    o.x = f2bf(v.x); o.y = f2bf(v.y); o.z = f2bf(v.z); o.w = f2bf(v.w);
    dst[i] = o;
  }
}

// ---- prep 2: W1 (K x N fp32, k-major) -> W1T (N x K bf16) ---------------
__global__ void transp_w1_k(const float* __restrict__ w1, u16* __restrict__ w1t) {
  __shared__ float tile[32][33];
  int n0 = blockIdx.x * 32;
  int k0 = blockIdx.y * 32;
  int tx = threadIdx.x;   // 0..31
  int ty = threadIdx.y;   // 0..7
#pragma unroll
  for (int i = 0; i < 32; i += 8)
    tile[ty + i][tx] = w1[(size_t)(k0 + ty + i) * H_ + n0 + tx];
  __syncthreads();
#pragma unroll
  for (int i = 0; i < 32; i += 8)
    w1t[(size_t)(n0 + ty + i) * K_ + k0 + tx] = f2bf(tile[tx][ty + i]);
}

// ---- main fused gather-GEMM + GELU + W2 partial contraction -------------
// LDS-traffic-minimized TLP structure: 128x128 tile, BK=64, 256 threads
// (4 waves, 2M x 2N). A (gathered) in LDS double-buffer (32KB total);
// B (W1T, affine + L2-resident) loaded DIRECTLY to registers each tile —
// no B LDS writes or reads. Per-CU LDS work drops below MFMA work for the
// first time; 3 blocks/CU (launch_bounds(256,3), 96KB LDS) give 3 waves/SIMD
// of independent blocks to cover B L2 latency + barrier drains via TLP.
// No manual waitcnt asm: plain loads + __syncthreads only.
// grid = 2048, XCD-swizzled (2048%8==0): each XCD = one batch (4MB = one L2).
__global__ __launch_bounds__(256, 3) void gemm_k(
    const u16*  __restrict__ hidB,   // bf16 hidden [B][S][H]
    const u16*  __restrict__ w1t,    // bf16 W1^T   [N=1024][K=2048]
    const int*  __restrict__ pairs,  // int32 [B][P][2]
    const float* __restrict__ b1,
    const float2* __restrict__ w2,   // W2 rows as float2
    float*      __restrict__ part)   // [16 q][32768 m] float2
{
  __shared__ u16 lds[2 * 8192];   // A only: 2 bufs x [128][64] u16 = 32KB

  // XCD-aware bijective swizzle (2048 % 8 == 0): 256 consecutive per XCD
  int orig = blockIdx.x;
  int bid = (orig & 7) * 256 + (orig >> 3);
  int nt = bid & 7;        // 8 N-tiles of 128
  int mt = bid >> 3;       // 256 M-tiles of 128
  int n0 = nt * 128;
  int m0 = mt * 128;
  int bI = m0 >> 12;       // batch index
  int pp = m0 & 4095;

  int t = threadIdx.x;     // 0..255
  int w = t >> 6;          // wave 0..3
  int l = t & 63;
  int lr = l & 15;
  int lj = l >> 4;
  int wr = w >> 1;         // wave row (M): 0..1 -> 64 rows each
  int wn = w & 1;          // wave col (N): 0..1 -> 64 cols each

  // staging source granule involution (write side of read-slot XOR)
  int gsrc = (l & 7) ^ ((l >> 3) & 7);
  // read-side granule slots (u16 offset): g = kk*4+lj, slot = g ^ (row&7),
  // row&7 == l&7 for all rows this lane reads
  unsigned xo[2];
  xo[0] = (unsigned)(((lj) ^ (l & 7)) * 8);
  xo[1] = (unsigned)(((4 + lj) ^ (l & 7)) * 8);

  // gather indices for staged rows r_i = i*32 + (t>>3)
  int2 sv[4];
#pragma unroll
  for (int i = 0; i < 4; ++i)
    sv[i] = ((const int2*)pairs)[bI * P_ + pp + i * 32 + (t >> 3)];

  const u16* hidBase = hidB + ((size_t)bI << 21);  // b * S_*H_
  const u16* bRowBase = w1t + (size_t)(n0 + wn * 64 + lr) * K_;

  f32x4 acc[4][4];
#pragma unroll
  for (int i = 0; i < 4; ++i)
#pragma unroll
    for (int j = 0; j < 4; ++j)
      acc[i][j] = (f32x4){0.f, 0.f, 0.f, 0.f};

  // stage A of K-tile T into buf: 4 x global_load_lds (16B/thread each)
  auto STAGE = [&](int buf, int T) {
    int k0 = T * 64;
    int kcol = k0 & 1023;     // column within selected half-row
    int half = k0 >> 10;      // 0 -> emb1, 1 -> emb2
    unsigned dbase = (unsigned)buf * 8192u + (unsigned)t * 8u;
#pragma unroll
    for (int i = 0; i < 4; ++i) {
      int s = half ? sv[i].y : sv[i].x;
      __builtin_amdgcn_global_load_lds(
          (const AS1 void*)(hidBase + (((size_t)s) << 10) + kcol + gsrc * 8),
          (AS3 void*)&lds[dbase + (unsigned)i * 2048u], 16, 0, 0);
    }
  };

  // prologue
  STAGE(0, 0);
  __syncthreads();

  for (int T = 0; T < NT_; ++T) {
    int cur = T & 1;
    if (T + 1 < NT_) STAGE(cur ^ 1, T + 1);

    // B fragments direct from L2 (plain loads; compiler manages vmcnt)
    bf16x8 bv[2][4];
#pragma unroll
    for (int kk = 0; kk < 2; ++kk)
#pragma unroll
      for (int ni = 0; ni < 4; ++ni)
        bv[kk][ni] = *(const bf16x8*)(bRowBase + (size_t)ni * 16 * K_ +
                                      T * 64 + kk * 32 + lj * 8);

    // A fragments from LDS
    bf16x8 af[2][4];
#pragma unroll
    for (int kk = 0; kk < 2; ++kk)
#pragma unroll
      for (int mi = 0; mi < 4; ++mi)
        af[kk][mi] = *(const bf16x8*)&lds[(unsigned)cur * 8192u +
            (unsigned)(wr * 64 + mi * 16 + lr) * 64u + xo[kk]];

    __builtin_amdgcn_s_setprio(1);
#pragma unroll
    for (int kk = 0; kk < 2; ++kk)
#pragma unroll
      for (int mi = 0; mi < 4; ++mi)
#pragma unroll
        for (int ni = 0; ni < 4; ++ni)
          acc[mi][ni] = __builtin_amdgcn_mfma_f32_16x16x32_bf16(
              af[kk][mi], bv[kk][ni], acc[mi][ni], 0, 0, 0);
    __builtin_amdgcn_s_setprio(0);
    __syncthreads();   // drain + barrier; co-resident blocks cover the stall
  }

  // ---- fused epilogue: bias + exact GELU + W2 contraction ----
  // acc element (mi,ni,j): row = wr*64+mi*16+lj*4+j, col = wn*64+ni*16+lr
  int q = nt * 2 + wn;
  float2* pOut = (float2*)part;
#pragma unroll
  for (int mi = 0; mi < 4; ++mi) {
    float s0[4] = {0.f, 0.f, 0.f, 0.f};
    float s1[4] = {0.f, 0.f, 0.f, 0.f};
#pragma unroll
    for (int ni = 0; ni < 4; ++ni) {
      int n = n0 + wn * 64 + ni * 16 + lr;
      float bb = b1[n];
      float2 wv = w2[n];
#pragma unroll
      for (int j = 0; j < 4; ++j) {
        float x = acc[mi][ni][j] + bb;
        float g = 0.5f * x * (1.0f + erff(x * 0.70710678118654752f));
        s0[j] += g * wv.x;
        s1[j] += g * wv.y;
      }
    }
#pragma unroll
    for (int off = 1; off < 16; off <<= 1) {
#pragma unroll
      for (int j = 0; j < 4; ++j) {
        s0[j] += __shfl_xor(s0[j], off, 64);
        s1[j] += __shfl_xor(s1[j], off, 64);
      }
    }
    if (lr == 0) {
#pragma unroll
      for (int j = 0; j < 4; ++j) {
        int m = m0 + wr * 64 + mi * 16 + lj * 4 + j;
        pOut[((size_t)q << 15) + m] = make_float2(s0[j], s1[j]);
      }
    }
  }
}

// ---- final reduce over 16 partials + b2 ---------------------------------
__global__ void reduce_k(const float2* __restrict__ part,
                         const float* __restrict__ b2,
                         float2* __restrict__ out) {
  int m = blockIdx.x * blockDim.x + threadIdx.x;
  if (m >= M_) return;
  float a0 = b2[0], a1 = b2[1];
#pragma unroll
  for (int q = 0; q < 16; ++q) {
    float2 v = part[((size_t)q << 15) + m];
    a0 += v.x; a1 += v.y;
  }
  out[m] = make_float2(a0, a1);
}

extern "C" void kernel_launch(void* const* d_in, const int* in_sizes, int n_in,
                              void* d_out, int out_size, void* d_ws, size_t ws_size,
                              hipStream_t stream) {
  const float* hidden = (const float*)d_in[0];
  const int*   pairs  = (const int*)d_in[1];
  const float* W1     = (const float*)d_in[2];
  const float* b1     = (const float*)d_in[3];
  const float* W2     = (const float*)d_in[4];
  const float* b2     = (const float*)d_in[5];
  float* out = (float*)d_out;

  // ws layout: hidden_bf16 (32 MiB) | W1T_bf16 (4 MiB) | partials (4 MiB)
  u16* hidB = (u16*)d_ws;
  u16* w1t  = hidB + (size_t)B_ * S_ * H_;
  float* part = (float*)(w1t + (size_t)H_ * K_);

  int n4 = (B_ * S_ * H_) / 4;
  cvt_hidden_k<<<4096, 256, 0, stream>>>((const float4*)hidden, (ushort4*)hidB, n4);
  transp_w1_k<<<dim3(H_ / 32, K_ / 32), dim3(32, 8), 0, stream>>>(W1, w1t);
  gemm_k<<<(M_ / 128) * (H_ / 128), 256, 0, stream>>>(
      hidB, w1t, pairs, b1, (const float2*)W2, part);
  reduce_k<<<(M_ + 255) / 256, 256, 0, stream>>>(
      (const float2*)part, b2, (float2*)out);
}

// Round 12
// 209.219 us; speedup vs baseline: 1.4676x; 1.4676x over previous
//
#include <hip/hip_runtime.h>
#include <hip/hip_bf16.h>

// Problem constants
#define B_  8
#define S_  2048
#define H_  1024
#define P_  4096

typedef unsigned short u16;
using bf16x8 = __attribute__((ext_vector_type(8))) short;   // 8 bf16 = 4 VGPRs
using f32x4  = __attribute__((ext_vector_type(4))) float;

#define AS1 __attribute__((address_space(1)))
#define AS3 __attribute__((address_space(3)))

__device__ inline u16 f2bf(float f) {
  union { float f; unsigned u; } c; c.f = f;
  unsigned u = c.u;
  unsigned r = (u + 0x7fffu + ((u >> 16) & 1u)) >> 16;  // RNE
  return (u16)r;
}
__device__ inline float bf2f(u16 v) {
  union { unsigned u; float f; } c; c.u = ((unsigned)v) << 16;
  return c.f;
}

// ---- prep 1: hidden fp32 -> bf16 (per-pass slice) -----------------------
__global__ void cvt_hidden_k(const float4* __restrict__ src,
                             ushort4* __restrict__ dst, int n4) {
  int i = blockIdx.x * blockDim.x + threadIdx.x;
  int stride = gridDim.x * blockDim.x;
  for (; i < n4; i += stride) {
    float4 v = src[i];
    ushort4 o;
    o.x = f2bf(v.x); o.y = f2bf(v.y); o.z = f2bf(v.z); o.w = f2bf(v.w);
    dst[i] = o;
  }
}

// ---- prep 2: W1 [2048][1024] fp32 -> bT [2048 n][1024 k] bf16 -----------
// bT[n][k] = W1[(n>>10)*1024 + k][n & 1023]   (top half | bottom half)
__global__ void transp_w1_k(const float* __restrict__ w1, u16* __restrict__ bT) {
  __shared__ float tile[32][33];
  int n0 = blockIdx.x * 32;            // 0..2047
  int k0 = blockIdx.y * 32;            // 0..1023
  int srcR = (n0 >> 10) * 1024 + k0;   // W1 row base
  int srcC = n0 & 1023;                // W1 col base
  int tx = threadIdx.x;   // 0..31
  int ty = threadIdx.y;   // 0..7
#pragma unroll
  for (int i = 0; i < 32; i += 8)
    tile[ty + i][tx] = w1[(size_t)(srcR + ty + i) * H_ + srcC + tx];
  __syncthreads();
#pragma unroll
  for (int i = 0; i < 32; i += 8)
    bT[(size_t)(n0 + ty + i) * 1024 + k0 + tx] = f2bf(tile[tx][ty + i]);
}

// ---- dense GEMM: C[Mp][2048] = A[Mp][1024] @ bT^T, bf16 out -------------
// R10 structure minus gather: 128x128 tile, BK=64, 256 thr (4 waves 2x2),
// dbuf LDS 64KB -> 2 blocks/CU; {stage t+1 | 16 frag reads | 32 MFMA/wave |
// syncthreads}. XCD-swizzled contiguous chunks (A set per XCD <= 4MB = L2).
__global__ __launch_bounds__(256, 2) void gemm_k(
    const u16* __restrict__ A,    // [Mp][1024] bf16
    const u16* __restrict__ bT,   // [2048][1024] bf16
    u16*       __restrict__ C,    // [Mp][2048] bf16
    int mtiles)                   // Mp / 128
{
  __shared__ u16 lds[2 * 16384];  // per buf: A[128][64] | B[128][64]

  int nblocks = mtiles * 16;
  int orig = blockIdx.x;
  int bid = (orig & 7) * (nblocks >> 3) + (orig >> 3);
  int nt = bid & 15;
  int mt = bid >> 4;
  int n0 = nt * 128;
  int m0 = mt * 128;

  int t = threadIdx.x;     // 0..255
  int w = t >> 6;          // wave 0..3
  int l = t & 63;
  int lr = l & 15;
  int lj = l >> 4;
  int wr = w >> 1;         // M half
  int wn = w & 1;          // N half

  // staging source granule involution; read-side slots (proven, 0 conflicts)
  int gsrc = (l & 7) ^ ((l >> 3) & 7);
  unsigned xo[2];
  xo[0] = (unsigned)(((lj) ^ (l & 7)) * 8);
  xo[1] = (unsigned)(((4 + lj) ^ (l & 7)) * 8);

  const u16* aBase = A  + (size_t)m0 * 1024;
  const u16* bBase = bT + (size_t)n0 * 1024;

  f32x4 acc[4][4];
#pragma unroll
  for (int i = 0; i < 4; ++i)
#pragma unroll
    for (int j = 0; j < 4; ++j)
      acc[i][j] = (f32x4){0.f, 0.f, 0.f, 0.f};

  auto STAGE = [&](int buf, int T) {
    int k0 = T * 64;
    unsigned dbase = (unsigned)buf * 16384u + (unsigned)t * 8u;
    int r = t >> 3;           // 0..31
#pragma unroll
    for (int i = 0; i < 4; ++i)
      __builtin_amdgcn_global_load_lds(
          (const AS1 void*)(aBase + (size_t)(i * 32 + r) * 1024 + k0 + gsrc * 8),
          (AS3 void*)&lds[dbase + (unsigned)i * 2048u], 16, 0, 0);
#pragma unroll
    for (int i = 0; i < 4; ++i)
      __builtin_amdgcn_global_load_lds(
          (const AS1 void*)(bBase + (size_t)(i * 32 + r) * 1024 + k0 + gsrc * 8),
          (AS3 void*)&lds[dbase + 8192u + (unsigned)i * 2048u], 16, 0, 0);
  };

  STAGE(0, 0);
  __syncthreads();

  for (int T = 0; T < 16; ++T) {
    int cur = T & 1;
    if (T + 1 < 16) STAGE(cur ^ 1, T + 1);

    bf16x8 af[2][4], bv[2][4];
#pragma unroll
    for (int kk = 0; kk < 2; ++kk) {
#pragma unroll
      for (int mi = 0; mi < 4; ++mi)
        af[kk][mi] = *(const bf16x8*)&lds[(unsigned)cur * 16384u +
            (unsigned)(wr * 64 + mi * 16 + lr) * 64u + xo[kk]];
#pragma unroll
      for (int ni = 0; ni < 4; ++ni)
        bv[kk][ni] = *(const bf16x8*)&lds[(unsigned)cur * 16384u + 8192u +
            (unsigned)(wn * 64 + ni * 16 + lr) * 64u + xo[kk]];
    }
    __builtin_amdgcn_s_setprio(1);
#pragma unroll
    for (int kk = 0; kk < 2; ++kk)
#pragma unroll
      for (int mi = 0; mi < 4; ++mi)
#pragma unroll
        for (int ni = 0; ni < 4; ++ni)
          acc[mi][ni] = __builtin_amdgcn_mfma_f32_16x16x32_bf16(
              af[kk][mi], bv[kk][ni], acc[mi][ni], 0, 0, 0);
    __builtin_amdgcn_s_setprio(0);
    __syncthreads();
  }

  // C-write (bf16): elem (mi,ni,j): row = wr*64+mi*16+lj*4+j, col = wn*64+ni*16+lr
#pragma unroll
  for (int mi = 0; mi < 4; ++mi)
#pragma unroll
    for (int ni = 0; ni < 4; ++ni)
#pragma unroll
      for (int j = 0; j < 4; ++j)
        C[(size_t)(m0 + wr * 64 + mi * 16 + lj * 4 + j) * 2048 +
          (n0 + wn * 64 + ni * 16 + lr)] = f2bf(acc[mi][ni][j]);
}

// ---- epilogue: logits[b,p] = GELU(U[s0]+V[s1]+b1) @ W2 + b2 -------------
// One wave per pair: lane owns 16 h-elements (n = l*16..+16). U-half and
// V-half row reads are fully coalesced (2 x b128 per row-half per lane).
__global__ __launch_bounds__(256) void gelu_w2_k(
    const u16* __restrict__ C,      // [nb*2048][2048] bf16 (pass-local)
    const int* __restrict__ pairs,  // int32 [B][P][2]
    const float* __restrict__ b1,
    const float2* __restrict__ w2,
    const float* __restrict__ b2,
    float2* __restrict__ out,       // [B*P]
    int b0, int nb)
{
  int nblocks = nb * 1024;
  int orig = blockIdx.x;
  int bid = (orig & 7) * (nblocks >> 3) + (orig >> 3);
  int w = threadIdx.x >> 6;
  int l = threadIdx.x & 63;
  int pr = bid * 4 + w;            // pair index within pass
  int bL = pr >> 12;               // local batch
  int p  = pr & 4095;
  int2 sv = ((const int2*)pairs)[(size_t)(b0 + bL) * P_ + p];

  const u16* Ub = C + (((size_t)(bL * 2048 + sv.x)) << 11) + l * 16;
  const u16* Vb = C + (((size_t)(bL * 2048 + sv.y)) << 11) + 1024 + l * 16;
  bf16x8 u0 = *(const bf16x8*)Ub;
  bf16x8 u1 = *(const bf16x8*)(Ub + 8);
  bf16x8 v0 = *(const bf16x8*)Vb;
  bf16x8 v1 = *(const bf16x8*)(Vb + 8);

  int n = l * 16;
  float o0 = 0.f, o1 = 0.f;
#pragma unroll
  for (int e = 0; e < 16; ++e) {
    u16 ue = (u16)(e < 8 ? u0[e] : u1[e - 8]);
    u16 ve = (u16)(e < 8 ? v0[e] : v1[e - 8]);
    float h = bf2f(ue) + bf2f(ve) + b1[n + e];
    float g = 0.5f * h * (1.0f + erff(h * 0.70710678118654752f));
    float2 wv = w2[n + e];
    o0 += g * wv.x;
    o1 += g * wv.y;
  }
#pragma unroll
  for (int off = 1; off < 64; off <<= 1) {
    o0 += __shfl_xor(o0, off, 64);
    o1 += __shfl_xor(o1, off, 64);
  }
  if (l == 0)
    out[(size_t)(b0 + bL) * P_ + p] = make_float2(o0 + b2[0], o1 + b2[1]);
}

extern "C" void kernel_launch(void* const* d_in, const int* in_sizes, int n_in,
                              void* d_out, int out_size, void* d_ws, size_t ws_size,
                              hipStream_t stream) {
  const float* hidden = (const float*)d_in[0];
  const int*   pairs  = (const int*)d_in[1];
  const float* W1     = (const float*)d_in[2];
  const float* b1     = (const float*)d_in[3];
  const float* W2     = (const float*)d_in[4];
  const float* b2     = (const float*)d_in[5];
  float* out = (float*)d_out;

  // ws: bT (4MB) | hidB (nb*4MB) | C (nb*8MB); need = 4 + 12*nb MB.
  const size_t MB = 1u << 20;
  int nb = 8;
  while (nb > 1 && ws_size < 4 * MB + (size_t)nb * 12 * MB) nb >>= 1;
  int np = 8 / nb;

  u16* bT   = (u16*)d_ws;                       // 2048*1024
  u16* hidB = bT + (size_t)2048 * 1024;         // nb*2048*1024
  u16* C    = hidB + (size_t)nb * 2048 * 1024;  // nb*2048*2048

  transp_w1_k<<<dim3(2048 / 32, 1024 / 32), dim3(32, 8), 0, stream>>>(W1, bT);

  for (int ps = 0; ps < np; ++ps) {
    int b0 = ps * nb;
    int n4 = nb * 2048 * 1024 / 4;
    cvt_hidden_k<<<2048, 256, 0, stream>>>(
        (const float4*)(hidden + (size_t)b0 * 2048 * 1024),
        (ushort4*)hidB, n4);
    int mtiles = nb * 16;                       // Mp/128
    gemm_k<<<mtiles * 16, 256, 0, stream>>>(hidB, bT, C, mtiles);
    gelu_w2_k<<<nb * 1024, 256, 0, stream>>>(
        C, pairs, b1, (const float2*)W2, b2, (float2*)out, b0, nb);
  }
}